// Round 13
// baseline (85.007 us; speedup 1.0000x reference)
//
#include <hip/hip_runtime.h>
#include <math.h>

#define N 8192
#define D 256
#define BK 32
#define TILE 128
#define NB (N / TILE)       // 64 panels
#define NSTRIP 1056         // sum over bi of ceil((64-bi)/2); 1056 = 8*132

typedef _Float16 half8 __attribute__((ext_vector_type(8)));
typedef float f32x4 __attribute__((ext_vector_type(4)));

constexpr float MARGIN = 0.5f;
constexpr float EPS_F  = 1e-10f;

// ---------------------------------------------------------------------------
// async global->LDS, 16B per lane. LDS dest = wave-uniform base + lane*16.
// ---------------------------------------------------------------------------
__device__ inline void load_lds16(const void* g, void* l) {
    __builtin_amdgcn_global_load_lds(
        (const __attribute__((address_space(1))) void*)g,
        (__attribute__((address_space(3))) void*)l, 16, 0, 0);
}

// ---------------------------------------------------------------------------
// Fused prologue (one dispatch, 512 blocks x 256 thr):
//   all blocks  : fp32 -> fp16 row-major convert + exact fp32 row sq-norms
//   blocks 0-15 : label detect/normalize + per-block 64-bin histogram slice
//   blocks 16-47: zero sum_same/sum_all
//   block 48    : zero out[0]
// ---------------------------------------------------------------------------
__global__ void prep_kernel(const float* __restrict__ xs,
                            const int* __restrict__ ys_raw,
                            _Float16* __restrict__ x16, float* __restrict__ sq,
                            int* __restrict__ lbl, int* __restrict__ hist16,
                            float* __restrict__ sums, float* __restrict__ out) {
    const int tid = threadIdx.x;
    const int rb  = blockIdx.x;

    {
        const int r   = tid >> 4;
        const int c16 = tid & 15;
        const int row = rb * 16 + r;

        const float4* src = (const float4*)xs + (size_t)row * (D / 4) + c16 * 4;
        const float4 v0 = src[0], v1 = src[1], v2 = src[2], v3 = src[3];

        half8 h0 = { (_Float16)v0.x, (_Float16)v0.y, (_Float16)v0.z, (_Float16)v0.w,
                     (_Float16)v1.x, (_Float16)v1.y, (_Float16)v1.z, (_Float16)v1.w };
        half8 h1 = { (_Float16)v2.x, (_Float16)v2.y, (_Float16)v2.z, (_Float16)v2.w,
                     (_Float16)v3.x, (_Float16)v3.y, (_Float16)v3.z, (_Float16)v3.w };

        _Float16* dst = x16 + (size_t)row * D + c16 * 16;
        *(half8*)dst       = h0;
        *(half8*)(dst + 8) = h1;

        float s = v0.x*v0.x + v0.y*v0.y + v0.z*v0.z + v0.w*v0.w
                + v1.x*v1.x + v1.y*v1.y + v1.z*v1.z + v1.w*v1.w
                + v2.x*v2.x + v2.y*v2.y + v2.z*v2.z + v2.w*v2.w
                + v3.x*v3.x + v3.y*v3.y + v3.z*v3.z + v3.w*v3.w;
#pragma unroll
        for (int off = 1; off < 16; off <<= 1) s += __shfl_xor(s, off);
        if (c16 == 0) sq[row] = s;
    }

    if (rb < 16) {
        __shared__ int bad_s;
        __shared__ int lh[64];
        const int base = rb * 512;
        if (tid == 0) bad_s = 0;
        if (tid < 64) lh[tid] = 0;
        __syncthreads();
        int bad = 0;
        for (int i = tid; i < 512; i += 256) bad |= (ys_raw[2 * (base + i) + 1] != 0);
        if (bad) atomicOr(&bad_s, 1);
        __syncthreads();
        const bool is64 = (bad_s == 0);
        for (int i = tid; i < 512; i += 256) {
            const int v = is64 ? ys_raw[2 * (base + i)] : ys_raw[base + i];
            lbl[base + i] = v;
            atomicAdd(&lh[v & 63], 1);
        }
        __syncthreads();
        if (tid < 64) hist16[rb * 64 + tid] = lh[tid];
    }

    if (rb >= 16 && rb < 48) {
        const int off = (rb - 16) * 512 + tid;
        sums[off]       = 0.f;
        sums[off + 256] = 0.f;
    }
    if (rb == 48 && tid == 0) out[0] = 0.f;
}

// ---------------------------------------------------------------------------
// Strip-lite pair kernel: block = row-panel bi x 2 adjacent column-panels,
// run back-to-back through the SAME depth-2 pipeline with no drain.
// Resources identical to the verified r10 point: 3 staging buffers (48 KB
// -> 3 blocks/CU), 4 gll/wave/stage, steady vmcnt(8), 2 barriers/iter,
// setprio on MFMA, launch_bounds(256,3). Per-panel r10-verified epilogue.
// ---------------------------------------------------------------------------
__global__ __launch_bounds__(256, 3) void pair_kernel(
    const _Float16* __restrict__ x16, const int* __restrict__ lbl,
    const float* __restrict__ sq,
    float* __restrict__ sum_same, float* __restrict__ sum_all) {

    __shared__ _Float16 As[3][TILE * BK];   // 24 KB
    __shared__ _Float16 Bs[3][TILE * BK];   // 24 KB

    // ---- XCD-bijective swizzle (1056 % 8 == 0 -> exact chunking) ----
    int rem = (blockIdx.x % 8) * (NSTRIP / 8) + blockIdx.x / 8;

    // ---- decode strip: bi, then bj0 = bi + 2*rem (r12-verified) ----
    int bi = 0;
    for (;;) {
        const int ns = (65 - bi) >> 1;     // ceil((64-bi)/2) strips for this bi
        if (rem < ns) break;
        rem -= ns;
        ++bi;
    }
    const int bj0   = bi + 2 * rem;
    const int npan  = (bj0 == 63) ? 1 : 2;
    const int total = npan * 8;            // k-iterations in this strip
    const int i0    = bi * TILE;

    const int tid  = threadIdx.x;
    const int w    = tid >> 6;
    const int lane = tid & 63;
    const int wm   = w >> 1;
    const int wn   = w & 1;
    const int cl   = lane & 15;
    const int g    = lane >> 4;

    const int rowbase = i0 + wm * 64;

    // staging: 512 16B-chunks per tile; chunk c -> row=c>>2, kc=c&3 (linear LDS)
    const int c0 = w * 64 + lane;
    const int r0 = c0 >> 2, kc0 = c0 & 3;
    const int c1 = 256 + c0;
    const int r1 = c1 >> 2, kc1 = c1 & 3;

    // every wave issues EXACTLY 4 global_load_lds per stage; epilogue atomics
    // and scalar loads only cause benign over-drain of counted waits.
#define STAGE(buf, jbase, k0)                                                   \
    do {                                                                        \
        load_lds16(x16 + (size_t)(i0 + r0) * D + (k0) + kc0 * 8,                \
                   &As[buf][(size_t)(w * 64) * 8]);                             \
        load_lds16(x16 + (size_t)((jbase) + r0) * D + (k0) + kc0 * 8,           \
                   &Bs[buf][(size_t)(w * 64) * 8]);                             \
        load_lds16(x16 + (size_t)(i0 + r1) * D + (k0) + kc1 * 8,                \
                   &As[buf][(size_t)(256 + w * 64) * 8]);                       \
        load_lds16(x16 + (size_t)((jbase) + r1) * D + (k0) + kc1 * 8,           \
                   &Bs[buf][(size_t)(256 + w * 64) * 8]);                       \
    } while (0)

    // prologue: tiles 0,1 of panel 0 in flight (8 loads)
    STAGE(0, bj0 * TILE, 0);
    STAGE(1, bj0 * TILE, BK);

    // panel-0 column operands (latency hidden under the k-loop)
    float sqj_[4];
    int   yj_[4];
#pragma unroll
    for (int nf = 0; nf < 4; ++nf) {
        const int c = bj0 * TILE + wn * 64 + nf * 16 + cl;
        sqj_[nf] = sq[c];
        yj_[nf]  = lbl[c];
    }

#pragma unroll 2
    for (int p = 0; p < 2; ++p) {
        if (p == 1 && npan == 1) break;
        const int  bj      = bj0 + p;
        const int  j0p     = bj * TILE;
        const bool diagp   = (bj == bi);
        const int  colbase = j0p + wn * 64;

        f32x4 acc[4][4];
#pragma unroll
        for (int a = 0; a < 4; ++a)
#pragma unroll
            for (int b = 0; b < 4; ++b) acc[a][b] = (f32x4){0.f, 0.f, 0.f, 0.f};

#pragma unroll
        for (int ks = 0; ks < 8; ++ks) {
            const int it  = p * 8 + ks;    // static within unrolled body
            const int cur = it % 3;
            const int u   = it + 2;        // tile staged this iter

            if (u < total) {               // wave-uniform; static for most iters
                const int pu  = u >> 3;
                const int k0n = (u & 7) * BK;
                STAGE(u % 3, (bj0 + pu) * TILE, k0n);
            }

            // counted waits: tile `it` is always the oldest outstanding stage
            if (it + 2 < total)      asm volatile("s_waitcnt vmcnt(8)" ::: "memory");
            else if (it + 1 < total) asm volatile("s_waitcnt vmcnt(4)" ::: "memory");
            else                     asm volatile("s_waitcnt vmcnt(0)" ::: "memory");
            __builtin_amdgcn_s_barrier();  // all waves' tile-`it` loads landed

            half8 af[4], bf[4];
#pragma unroll
            for (int mf = 0; mf < 4; ++mf)
                af[mf] = *(const half8*)&As[cur][(wm * 64 + mf * 16 + cl) * BK + g * 8];
#pragma unroll
            for (int nf = 0; nf < 4; ++nf)
                bf[nf] = *(const half8*)&Bs[cur][(wn * 64 + nf * 16 + cl) * BK + g * 8];

            __builtin_amdgcn_s_setprio(1);
#pragma unroll
            for (int mf = 0; mf < 4; ++mf)
#pragma unroll
                for (int nf = 0; nf < 4; ++nf)
                    acc[mf][nf] = __builtin_amdgcn_mfma_f32_16x16x32_f16(
                        af[mf], bf[nf], acc[mf][nf], 0, 0, 0);
            __builtin_amdgcn_s_setprio(0);

            // all waves consumed buf[cur] -> next iter's stage may overwrite it
            if (it + 1 < total) __builtin_amdgcn_s_barrier();
        }

        // ---- panel epilogue (r10-verified; no LDS, shfl + atomics only).
        // Runs while the next panel's tiles are in flight -> latency hidden.
        // C layout (m89): col = lane&15 (j-local), row = (lane>>4)*4+reg.
        float cs_all[4], cs_same[4];
#pragma unroll
        for (int nf = 0; nf < 4; ++nf) { cs_all[nf] = 0.f; cs_same[nf] = 0.f; }

#pragma unroll
        for (int b = 0; b < 2; ++b) {
            float rs_all[8], rs_same[8];
#pragma unroll
            for (int e = 0; e < 8; ++e) { rs_all[e] = 0.f; rs_same[e] = 0.f; }

#pragma unroll
            for (int mh = 0; mh < 2; ++mh) {
                const int mf = 2 * b + mh;
#pragma unroll
                for (int r = 0; r < 4; ++r) {
                    const int row   = rowbase + mf * 16 + g * 4 + r;
                    const float sqi = sq[row];
                    const int   yi  = lbl[row];
#pragma unroll
                    for (int nf = 0; nf < 4; ++nf) {
                        float d2   = sqi + sqj_[nf] - 2.f * acc[mf][nf][r];
                        float dist = __builtin_amdgcn_sqrtf(fmaxf(d2, EPS_F));
                        if (diagp) {
                            const int col = colbase + nf * 16 + cl;
                            if (row == col) dist = 1e-5f;  // exact diag sqrt(EPS)
                        }
                        const float dm = (yi == yj_[nf]) ? dist : 0.f;
                        cs_all[nf] += dist;
                        cs_same[nf] += dm;
                        rs_all[mh * 4 + r] += dist;
                        rs_same[mh * 4 + r] += dm;
                    }
                }
            }

            // row direction (off-diag only): value-split 8 over 16 lanes +
            // closing mask-1 stage; even-cl lanes own entry e = cl>>1.
            if (!diagp) {
#define RSTEP(h, mask, bit)                                                     \
                {                                                               \
                    const bool hi = (cl >> (bit)) & 1;                          \
                    _Pragma("unroll")                                           \
                    for (int j = 0; j < (h); ++j) {                             \
                        float sa_ = hi ? rs_all[j] : rs_all[j + (h)];           \
                        float ka_ = hi ? rs_all[j + (h)] : rs_all[j];           \
                        rs_all[j] = ka_ + __shfl_xor(sa_, (mask));              \
                        float ss_ = hi ? rs_same[j] : rs_same[j + (h)];         \
                        float ks_ = hi ? rs_same[j + (h)] : rs_same[j];         \
                        rs_same[j] = ks_ + __shfl_xor(ss_, (mask));             \
                    }                                                           \
                }
                RSTEP(4, 8, 3)
                RSTEP(2, 4, 2)
                RSTEP(1, 2, 1)
#undef RSTEP
                rs_all[0]  += __shfl_xor(rs_all[0], 1);   // closing stage
                rs_same[0] += __shfl_xor(rs_same[0], 1);

                const int e    = cl >> 1;
                const int rrow = rowbase + (2 * b + (e >> 2)) * 16 + g * 4 + (e & 3);
                if (!(cl & 1)) {
                    atomicAdd(&sum_all[rrow],  rs_all[0]);
                    atomicAdd(&sum_same[rrow], rs_same[0]);
                }
            }
        }

        // col direction: value-split reduce 4 values over 4 g-lanes
        {
            const bool hi1 = (g >> 1) & 1;
#pragma unroll
            for (int j = 0; j < 2; ++j) {
                float sa_ = hi1 ? cs_all[j] : cs_all[j + 2];
                float ka_ = hi1 ? cs_all[j + 2] : cs_all[j];
                cs_all[j] = ka_ + __shfl_xor(sa_, 32);
                float ss_ = hi1 ? cs_same[j] : cs_same[j + 2];
                float ks_ = hi1 ? cs_same[j + 2] : cs_same[j];
                cs_same[j] = ks_ + __shfl_xor(ss_, 32);
            }
            const bool hi0 = g & 1;
            {
                float sa_ = hi0 ? cs_all[0] : cs_all[1];
                float ka_ = hi0 ? cs_all[1] : cs_all[0];
                cs_all[0] = ka_ + __shfl_xor(sa_, 16);
                float ss_ = hi0 ? cs_same[0] : cs_same[1];
                float ks_ = hi0 ? cs_same[1] : cs_same[0];
                cs_same[0] = ks_ + __shfl_xor(ss_, 16);
            }
            const int ccol = colbase + g * 16 + cl;
            atomicAdd(&sum_all[ccol],  cs_all[0]);
            atomicAdd(&sum_same[ccol], cs_same[0]);
        }

        // next panel's column operands (consumed ~8 k-iters later)
        if (p == 0 && npan == 2) {
#pragma unroll
            for (int nf = 0; nf < 4; ++nf) {
                const int c = (bj0 + 1) * TILE + wn * 64 + nf * 16 + cl;
                sqj_[nf] = sq[c];
                yj_[nf]  = lbl[c];
            }
        }
    }
#undef STAGE
}

// ---------------------------------------------------------------------------
// Finalize: 32 blocks x 256 thr, one row per thread. Histogram from the 16
// precomputed slices.
// ---------------------------------------------------------------------------
__global__ void finalize_kernel(const float* __restrict__ sum_same,
                                const float* __restrict__ sum_all,
                                const int* __restrict__ lbl,
                                const int* __restrict__ hist16,
                                float* __restrict__ out) {
    __shared__ int lh[64];
    __shared__ float wsums[4];
    const int tid = threadIdx.x;
    if (tid < 64) {
        int h = 0;
#pragma unroll
        for (int b = 0; b < 16; ++b) h += hist16[b * 64 + tid];
        lh[tid] = h;
    }
    __syncthreads();

    const int row = blockIdx.x * 256 + tid;
    const float cnt = (float)lh[lbl[row]];
    const float ss  = sum_same[row];
    const float sa  = sum_all[row];
    const float ap  = ss / cnt;
    const float an  = (sa - ss) / ((float)N - cnt);
    float local = fmaxf(ap - an + MARGIN, 0.f);

#pragma unroll
    for (int off = 32; off > 0; off >>= 1) local += __shfl_down(local, off);
    const int lane = tid & 63, wave = tid >> 6;
    if (lane == 0) wsums[wave] = local;
    __syncthreads();
    if (tid == 0)
        atomicAdd(out, (wsums[0] + wsums[1] + wsums[2] + wsums[3]) / (float)N);
}

// ---------------------------------------------------------------------------
extern "C" void kernel_launch(void* const* d_in, const int* in_sizes, int n_in,
                              void* d_out, int out_size, void* d_ws, size_t ws_size,
                              hipStream_t stream) {
    const float* xs     = (const float*)d_in[0];
    const int*   ys_raw = (const int*)d_in[1];

    float* ws       = (float*)d_ws;
    float* sum_same = ws;                          // [N]
    float* sum_all  = ws + N;                      // [N]
    float* sqv      = ws + 2 * N;                  // [N]
    int*   lbl      = (int*)(ws + 3 * N);          // [N]
    int*   hist16   = (int*)(ws + 4 * N);          // [16*64]
    _Float16* x16   = (_Float16*)(ws + 4 * N + 1024);  // [N*D] fp16 (4 MB)

    prep_kernel<<<N / 16, 256, 0, stream>>>(xs, ys_raw, x16, sqv, lbl, hist16,
                                            sum_same, (float*)d_out);

    pair_kernel<<<NSTRIP, 256, 0, stream>>>(x16, lbl, sqv, sum_same, sum_all);

    finalize_kernel<<<32, 256, 0, stream>>>(sum_same, sum_all, lbl, hist16,
                                            (float*)d_out);
}

// Round 14
// 75.027 us; speedup vs baseline: 1.1330x; 1.1330x over previous
//
#include <hip/hip_runtime.h>
#include <math.h>

#define N 8192
#define D 256
#define BK 32
#define TILE 256
#define NB2 (N / TILE)                 // 32 panels of 256 rows
#define NBLK2 (NB2 * (NB2 + 1) / 2)    // 528 upper-triangular blocks (528%8==0)

typedef _Float16 half8 __attribute__((ext_vector_type(8)));
typedef float f32x4 __attribute__((ext_vector_type(4)));

constexpr float MARGIN = 0.5f;
constexpr float EPS_F  = 1e-10f;

// ---------------------------------------------------------------------------
// async global->LDS, 16B per lane. LDS dest = wave-uniform base + lane*16.
// ---------------------------------------------------------------------------
__device__ inline void load_lds16(const void* g, void* l) {
    __builtin_amdgcn_global_load_lds(
        (const __attribute__((address_space(1))) void*)g,
        (__attribute__((address_space(3))) void*)l, 16, 0, 0);
}

// ---------------------------------------------------------------------------
// Fused prologue (one dispatch, 512 blocks x 256 thr):
//   all blocks  : fp32 -> fp16 row-major convert + exact fp32 row sq-norms
//   blocks 0-15 : label detect/normalize + per-block 64-bin histogram slice
//   blocks 16-47: zero sum_same/sum_all
//   block 48    : zero out[0]
// ---------------------------------------------------------------------------
__global__ void prep_kernel(const float* __restrict__ xs,
                            const int* __restrict__ ys_raw,
                            _Float16* __restrict__ x16, float* __restrict__ sq,
                            int* __restrict__ lbl, int* __restrict__ hist16,
                            float* __restrict__ sums, float* __restrict__ out) {
    const int tid = threadIdx.x;
    const int rb  = blockIdx.x;

    {
        const int r   = tid >> 4;
        const int c16 = tid & 15;
        const int row = rb * 16 + r;

        const float4* src = (const float4*)xs + (size_t)row * (D / 4) + c16 * 4;
        const float4 v0 = src[0], v1 = src[1], v2 = src[2], v3 = src[3];

        half8 h0 = { (_Float16)v0.x, (_Float16)v0.y, (_Float16)v0.z, (_Float16)v0.w,
                     (_Float16)v1.x, (_Float16)v1.y, (_Float16)v1.z, (_Float16)v1.w };
        half8 h1 = { (_Float16)v2.x, (_Float16)v2.y, (_Float16)v2.z, (_Float16)v2.w,
                     (_Float16)v3.x, (_Float16)v3.y, (_Float16)v3.z, (_Float16)v3.w };

        _Float16* dst = x16 + (size_t)row * D + c16 * 16;
        *(half8*)dst       = h0;
        *(half8*)(dst + 8) = h1;

        float s = v0.x*v0.x + v0.y*v0.y + v0.z*v0.z + v0.w*v0.w
                + v1.x*v1.x + v1.y*v1.y + v1.z*v1.z + v1.w*v1.w
                + v2.x*v2.x + v2.y*v2.y + v2.z*v2.z + v2.w*v2.w
                + v3.x*v3.x + v3.y*v3.y + v3.z*v3.z + v3.w*v3.w;
#pragma unroll
        for (int off = 1; off < 16; off <<= 1) s += __shfl_xor(s, off);
        if (c16 == 0) sq[row] = s;
    }

    if (rb < 16) {
        __shared__ int bad_s;
        __shared__ int lh[64];
        const int base = rb * 512;
        if (tid == 0) bad_s = 0;
        if (tid < 64) lh[tid] = 0;
        __syncthreads();
        int bad = 0;
        for (int i = tid; i < 512; i += 256) bad |= (ys_raw[2 * (base + i) + 1] != 0);
        if (bad) atomicOr(&bad_s, 1);
        __syncthreads();
        const bool is64 = (bad_s == 0);
        for (int i = tid; i < 512; i += 256) {
            const int v = is64 ? ys_raw[2 * (base + i)] : ys_raw[base + i];
            lbl[base + i] = v;
            atomicAdd(&lh[v & 63], 1);
        }
        __syncthreads();
        if (tid < 64) hist16[rb * 64 + tid] = lh[tid];
    }

    if (rb >= 16 && rb < 48) {
        const int off = (rb - 16) * 512 + tid;
        sums[off]       = 0.f;
        sums[off + 256] = 0.f;
    }
    if (rb == 48 && tid == 0) out[0] = 0.f;
}

// ---------------------------------------------------------------------------
// 256x256-tile symmetric MFMA pair kernel, r10 schedule scaled up:
// 512 threads = 8 waves (2 wm x 4 wn), per-wave output 128x64 (acc 8x4).
// 3 staging buffers (96 KB), depth-2 prefetch, per-wave-exact 4 gll/stage,
// steady vmcnt(8), 2 barriers/iter, setprio on MFMA, operand hoist last iter.
// Epilogue: r7/r10-verified math, 4 row-batches of 8. 528 upper-tri blocks.
// ---------------------------------------------------------------------------
__global__ __launch_bounds__(512, 2) void pair_kernel(
    const _Float16* __restrict__ x16, const int* __restrict__ lbl,
    const float* __restrict__ sq,
    float* __restrict__ sum_same, float* __restrict__ sum_all) {

    __shared__ _Float16 As[3][TILE * BK];   // 48 KB
    __shared__ _Float16 Bs[3][TILE * BK];   // 48 KB

    // ---- XCD-bijective swizzle (528 % 8 == 0 -> exact chunking) ----
    const int t = (blockIdx.x % 8) * (NBLK2 / 8) + blockIdx.x / 8;

    // ---- decode upper-triangular block index: t -> (bi, bj), bi<=bj ----
    int bj = (int)((sqrtf(8.f * (float)t + 1.f) - 1.f) * 0.5f);
    while ((bj + 1) * (bj + 2) / 2 <= t) ++bj;
    while (bj * (bj + 1) / 2 > t) --bj;
    const int bi    = t - bj * (bj + 1) / 2;
    const bool diag = (bi == bj);
    const int i0 = bi * TILE;
    const int j0 = bj * TILE;

    const int tid  = threadIdx.x;
    const int w    = tid >> 6;        // 0..7
    const int lane = tid & 63;
    const int wm   = w >> 2;          // 0..1 (row half: 128 rows)
    const int wn   = w & 3;           // 0..3 (col quarter: 64 cols)
    const int cl   = lane & 15;
    const int g    = lane >> 4;

    const int rowbase = i0 + wm * 128;
    const int colbase = j0 + wn * 64;

    f32x4 acc[8][4];
#pragma unroll
    for (int a = 0; a < 8; ++a)
#pragma unroll
        for (int b = 0; b < 4; ++b) acc[a][b] = (f32x4){0.f, 0.f, 0.f, 0.f};

    // staging: A tile 256x32 fp16 = 1024 16B-chunks, B same. Thread handles
    // chunks c0 and c0+512 of each; chunk c -> row=c>>2, kc=c&3 (linear LDS).
    // Every wave issues EXACTLY 4 global_load_lds per stage -> vmcnt exact.
    const int c0 = w * 64 + lane;     // 0..511
    const int r0 = c0 >> 2, kc0 = c0 & 3;
    const int r1 = r0 + 128;          // chunk c0+512

#define STAGE(buf, k0)                                                          \
    do {                                                                        \
        load_lds16(x16 + (size_t)(i0 + r0) * D + (k0) + kc0 * 8,                \
                   &As[buf][(size_t)(w * 64) * 8]);                             \
        load_lds16(x16 + (size_t)(j0 + r0) * D + (k0) + kc0 * 8,                \
                   &Bs[buf][(size_t)(w * 64) * 8]);                             \
        load_lds16(x16 + (size_t)(i0 + r1) * D + (k0) + kc0 * 8,                \
                   &As[buf][(size_t)(512 + w * 64) * 8]);                       \
        load_lds16(x16 + (size_t)(j0 + r1) * D + (k0) + kc0 * 8,                \
                   &Bs[buf][(size_t)(512 + w * 64) * 8]);                       \
    } while (0)

    STAGE(0, 0);           // prologue: stages 0 and 1 in flight (8 loads)
    STAGE(1, BK);

    float sqj_[4];
    int   yj_[4];

#pragma unroll
    for (int t8 = 0; t8 < 8; ++t8) {          // fully unrolled -> static %3
        const int cur = t8 % 3;
        if (t8 < 6) STAGE((t8 + 2) % 3, (t8 + 2) * BK);   // keep 2 stages ahead

        // wait for stage t8 only: 2 newer stages (8 loads) may stay in flight
        if (t8 < 6)       asm volatile("s_waitcnt vmcnt(8)" ::: "memory");
        else if (t8 == 6) asm volatile("s_waitcnt vmcnt(4)" ::: "memory");
        else              asm volatile("s_waitcnt vmcnt(0)" ::: "memory");
        __builtin_amdgcn_s_barrier();   // all waves' stage-t8 loads landed

        // last iter: issue epilogue operand loads; latency hides under MFMAs
        if (t8 == 7) {
#pragma unroll
            for (int nf = 0; nf < 4; ++nf) {
                const int c = colbase + nf * 16 + cl;
                sqj_[nf] = sq[c];
                yj_[nf]  = lbl[c];
            }
        }

        half8 af[8], bf[4];
#pragma unroll
        for (int mf = 0; mf < 8; ++mf)
            af[mf] = *(const half8*)&As[cur][(wm * 128 + mf * 16 + cl) * BK + g * 8];
#pragma unroll
        for (int nf = 0; nf < 4; ++nf)
            bf[nf] = *(const half8*)&Bs[cur][(wn * 64 + nf * 16 + cl) * BK + g * 8];

        __builtin_amdgcn_s_setprio(1);
#pragma unroll
        for (int mf = 0; mf < 8; ++mf)
#pragma unroll
            for (int nf = 0; nf < 4; ++nf)
                acc[mf][nf] = __builtin_amdgcn_mfma_f32_16x16x32_f16(
                    af[mf], bf[nf], acc[mf][nf], 0, 0, 0);
        __builtin_amdgcn_s_setprio(0);

        // all waves consumed buf[cur] -> next iter's stage may overwrite it
        if (t8 < 7) __builtin_amdgcn_s_barrier();
    }
#undef STAGE

    // ---- epilogue (r7/r10-verified math, 4 batches of 8 rows) ----
    // C layout (m89): col = lane&15 (j-local), row = (lane>>4)*4 + reg (i-local)
    float cs_all[4], cs_same[4];      // col sums (over i) -> rows of panel bj
#pragma unroll
    for (int nf = 0; nf < 4; ++nf) { cs_all[nf] = 0.f; cs_same[nf] = 0.f; }

#pragma unroll
    for (int b = 0; b < 4; ++b) {
        float rs_all[8], rs_same[8];
#pragma unroll
        for (int e = 0; e < 8; ++e) { rs_all[e] = 0.f; rs_same[e] = 0.f; }

#pragma unroll
        for (int mh = 0; mh < 2; ++mh) {
            const int mf = 2 * b + mh;
#pragma unroll
            for (int r = 0; r < 4; ++r) {
                const int row   = rowbase + mf * 16 + g * 4 + r;
                const float sqi = sq[row];
                const int   yi  = lbl[row];
#pragma unroll
                for (int nf = 0; nf < 4; ++nf) {
                    float d2   = sqi + sqj_[nf] - 2.f * acc[mf][nf][r];
                    float dist = __builtin_amdgcn_sqrtf(fmaxf(d2, EPS_F));
                    if (diag) {
                        const int col = colbase + nf * 16 + cl;
                        if (row == col) dist = 1e-5f;   // exact diagonal sqrt(EPS)
                    }
                    const float dm = (yi == yj_[nf]) ? dist : 0.f;
                    cs_all[nf] += dist;
                    cs_same[nf] += dm;
                    rs_all[mh * 4 + r] += dist;
                    rs_same[mh * 4 + r] += dm;
                }
            }
        }

        // row direction (off-diag only): value-split 8 values over 16 lanes +
        // closing mask-1 stage; even-cl lanes own entry e = cl>>1.
        if (!diag) {
#define RSTEP(h, mask, bit)                                                     \
            {                                                                   \
                const bool hi = (cl >> (bit)) & 1;                              \
                _Pragma("unroll")                                               \
                for (int j = 0; j < (h); ++j) {                                 \
                    float sa_ = hi ? rs_all[j] : rs_all[j + (h)];               \
                    float ka_ = hi ? rs_all[j + (h)] : rs_all[j];               \
                    rs_all[j] = ka_ + __shfl_xor(sa_, (mask));                  \
                    float ss_ = hi ? rs_same[j] : rs_same[j + (h)];             \
                    float ks_ = hi ? rs_same[j + (h)] : rs_same[j];             \
                    rs_same[j] = ks_ + __shfl_xor(ss_, (mask));                 \
                }                                                               \
            }
            RSTEP(4, 8, 3)
            RSTEP(2, 4, 2)
            RSTEP(1, 2, 1)
#undef RSTEP
            rs_all[0]  += __shfl_xor(rs_all[0], 1);   // closing stage (mask 1)
            rs_same[0] += __shfl_xor(rs_same[0], 1);

            const int e    = cl >> 1;
            const int rrow = rowbase + (2 * b + (e >> 2)) * 16 + g * 4 + (e & 3);
            if (!(cl & 1)) {
                atomicAdd(&sum_all[rrow],  rs_all[0]);
                atomicAdd(&sum_same[rrow], rs_same[0]);
            }
        }
    }

    // ---- col direction: value-split reduce 4 values over 4 g-lanes
    {
        const bool hi1 = (g >> 1) & 1;
#pragma unroll
        for (int j = 0; j < 2; ++j) {
            float sa_ = hi1 ? cs_all[j] : cs_all[j + 2];
            float ka_ = hi1 ? cs_all[j + 2] : cs_all[j];
            cs_all[j] = ka_ + __shfl_xor(sa_, 32);
            float ss_ = hi1 ? cs_same[j] : cs_same[j + 2];
            float ks_ = hi1 ? cs_same[j + 2] : cs_same[j];
            cs_same[j] = ks_ + __shfl_xor(ss_, 32);
        }
        const bool hi0 = g & 1;
        {
            float sa_ = hi0 ? cs_all[0] : cs_all[1];
            float ka_ = hi0 ? cs_all[1] : cs_all[0];
            cs_all[0] = ka_ + __shfl_xor(sa_, 16);
            float ss_ = hi0 ? cs_same[0] : cs_same[1];
            float ks_ = hi0 ? cs_same[1] : cs_same[0];
            cs_same[0] = ks_ + __shfl_xor(ss_, 16);
        }
        const int ccol = colbase + g * 16 + cl;
        atomicAdd(&sum_all[ccol],  cs_all[0]);
        atomicAdd(&sum_same[ccol], cs_same[0]);
    }
}

// ---------------------------------------------------------------------------
// Finalize: 32 blocks x 256 thr, one row per thread. Histogram from the 16
// precomputed slices.
// ---------------------------------------------------------------------------
__global__ void finalize_kernel(const float* __restrict__ sum_same,
                                const float* __restrict__ sum_all,
                                const int* __restrict__ lbl,
                                const int* __restrict__ hist16,
                                float* __restrict__ out) {
    __shared__ int lh[64];
    __shared__ float wsums[4];
    const int tid = threadIdx.x;
    if (tid < 64) {
        int h = 0;
#pragma unroll
        for (int b = 0; b < 16; ++b) h += hist16[b * 64 + tid];
        lh[tid] = h;
    }
    __syncthreads();

    const int row = blockIdx.x * 256 + tid;
    const float cnt = (float)lh[lbl[row]];
    const float ss  = sum_same[row];
    const float sa  = sum_all[row];
    const float ap  = ss / cnt;
    const float an  = (sa - ss) / ((float)N - cnt);
    float local = fmaxf(ap - an + MARGIN, 0.f);

#pragma unroll
    for (int off = 32; off > 0; off >>= 1) local += __shfl_down(local, off);
    const int lane = tid & 63, wave = tid >> 6;
    if (lane == 0) wsums[wave] = local;
    __syncthreads();
    if (tid == 0)
        atomicAdd(out, (wsums[0] + wsums[1] + wsums[2] + wsums[3]) / (float)N);
}

// ---------------------------------------------------------------------------
extern "C" void kernel_launch(void* const* d_in, const int* in_sizes, int n_in,
                              void* d_out, int out_size, void* d_ws, size_t ws_size,
                              hipStream_t stream) {
    const float* xs     = (const float*)d_in[0];
    const int*   ys_raw = (const int*)d_in[1];

    float* ws       = (float*)d_ws;
    float* sum_same = ws;                          // [N]
    float* sum_all  = ws + N;                      // [N]
    float* sqv      = ws + 2 * N;                  // [N]
    int*   lbl      = (int*)(ws + 3 * N);          // [N]
    int*   hist16   = (int*)(ws + 4 * N);          // [16*64]
    _Float16* x16   = (_Float16*)(ws + 4 * N + 1024);  // [N*D] fp16 (4 MB)

    prep_kernel<<<N / 16, 256, 0, stream>>>(xs, ys_raw, x16, sqv, lbl, hist16,
                                            sum_same, (float*)d_out);

    pair_kernel<<<NBLK2, 512, 0, stream>>>(x16, lbl, sqv, sum_same, sum_all);

    finalize_kernel<<<32, 256, 0, stream>>>(sum_same, sum_all, lbl, hist16,
                                            (float*)d_out);
}

// Round 15
// 51.064 us; speedup vs baseline: 1.6647x; 1.4693x over previous
//
#include <hip/hip_runtime.h>
#include <math.h>

#define N 8192
#define D 256
#define BK 32
#define TILE 128
#define NB (N / TILE)              // 64 panels
#define NBLK (NB * (NB + 1) / 2)   // 2080 upper-triangular blocks

typedef _Float16 half8 __attribute__((ext_vector_type(8)));
typedef float f32x4 __attribute__((ext_vector_type(4)));

constexpr float MARGIN = 0.5f;
constexpr float EPS_F  = 1e-10f;

// ---------------------------------------------------------------------------
// async global->LDS, 16B per lane. LDS dest = wave-uniform base + lane*16.
// ---------------------------------------------------------------------------
__device__ inline void load_lds16(const void* g, void* l) {
    __builtin_amdgcn_global_load_lds(
        (const __attribute__((address_space(1))) void*)g,
        (__attribute__((address_space(3))) void*)l, 16, 0, 0);
}

// ---------------------------------------------------------------------------
// Fused prologue (one dispatch, 512 blocks x 256 thr):
//   all blocks  : fp32 -> fp16 row-major convert + exact fp32 row sq-norms
//   blocks 0-15 : label detect/normalize + per-block 64-bin histogram slice
//   blocks 16-47: zero the 8 per-XCD partial sum arrays (16N floats)
//   block 48    : zero out[0]
// ---------------------------------------------------------------------------
__global__ void prep_kernel(const float* __restrict__ xs,
                            const int* __restrict__ ys_raw,
                            _Float16* __restrict__ x16, float* __restrict__ sq,
                            int* __restrict__ lbl, int* __restrict__ hist16,
                            float* __restrict__ sums, float* __restrict__ out) {
    const int tid = threadIdx.x;
    const int rb  = blockIdx.x;

    // ---- convert + sq (every block handles a 16-row tile) ----
    {
        const int r   = tid >> 4;
        const int c16 = tid & 15;
        const int row = rb * 16 + r;

        const float4* src = (const float4*)xs + (size_t)row * (D / 4) + c16 * 4;
        const float4 v0 = src[0], v1 = src[1], v2 = src[2], v3 = src[3];

        half8 h0 = { (_Float16)v0.x, (_Float16)v0.y, (_Float16)v0.z, (_Float16)v0.w,
                     (_Float16)v1.x, (_Float16)v1.y, (_Float16)v1.z, (_Float16)v1.w };
        half8 h1 = { (_Float16)v2.x, (_Float16)v2.y, (_Float16)v2.z, (_Float16)v2.w,
                     (_Float16)v3.x, (_Float16)v3.y, (_Float16)v3.z, (_Float16)v3.w };

        _Float16* dst = x16 + (size_t)row * D + c16 * 16;
        *(half8*)dst       = h0;
        *(half8*)(dst + 8) = h1;

        float s = v0.x*v0.x + v0.y*v0.y + v0.z*v0.z + v0.w*v0.w
                + v1.x*v1.x + v1.y*v1.y + v1.z*v1.z + v1.w*v1.w
                + v2.x*v2.x + v2.y*v2.y + v2.z*v2.z + v2.w*v2.w
                + v3.x*v3.x + v3.y*v3.y + v3.z*v3.z + v3.w*v3.w;
#pragma unroll
        for (int off = 1; off < 16; off <<= 1) s += __shfl_xor(s, off);
        if (c16 == 0) sq[row] = s;
    }

    // ---- labels + histogram slice (blocks 0-15, 512 labels each) ----
    if (rb < 16) {
        __shared__ int bad_s;
        __shared__ int lh[64];
        const int base = rb * 512;
        if (tid == 0) bad_s = 0;
        if (tid < 64) lh[tid] = 0;
        __syncthreads();
        int bad = 0;
        for (int i = tid; i < 512; i += 256) bad |= (ys_raw[2 * (base + i) + 1] != 0);
        if (bad) atomicOr(&bad_s, 1);
        __syncthreads();
        const bool is64 = (bad_s == 0);
        for (int i = tid; i < 512; i += 256) {
            const int v = is64 ? ys_raw[2 * (base + i)] : ys_raw[base + i];
            lbl[base + i] = v;
            atomicAdd(&lh[v & 63], 1);
        }
        __syncthreads();
        if (tid < 64) hist16[rb * 64 + tid] = lh[tid];   // exclusive slice
    }

    // ---- zero per-XCD partials (blocks 16-47: 32 blocks x 4096 floats = 16N) ----
    if (rb >= 16 && rb < 48) {
        const int base = (rb - 16) * 4096;
#pragma unroll
        for (int k = 0; k < 16; ++k) sums[base + k * 256 + tid] = 0.f;
    }
    if (rb == 48 && tid == 0) out[0] = 0.f;
}

// ---------------------------------------------------------------------------
// Symmetric MFMA pair kernel (r10-verified base), depth-2 LDS pipeline:
// 3 staging buffers (48 KB), counted vmcnt(8) steady state, 2 raw barriers
// per k-iter, setprio on MFMA, epilogue operand hoist in last iter.
// 128x128 tile, 4 waves (2x2 of 64x64), mfma_f32_16x16x32_f16.
// NEW (this round): atomics target per-XCD partial arrays sum[xcd][row]
// (xcd = blockIdx.x & 7 == resident XCD under round-robin dispatch) so
// atomic cache lines never migrate across XCDs.
// ---------------------------------------------------------------------------
__global__ __launch_bounds__(256, 3) void pair_kernel(
    const _Float16* __restrict__ x16, const int* __restrict__ lbl,
    const float* __restrict__ sq,
    float* __restrict__ sum_same8, float* __restrict__ sum_all8) {

    __shared__ _Float16 As[3][TILE * BK];   // 24 KB
    __shared__ _Float16 Bs[3][TILE * BK];   // 24 KB

    // ---- XCD-bijective swizzle (2080 % 8 == 0 -> exact chunking) ----
    const int xcd = blockIdx.x & 7;         // == XCD under round-robin dispatch
    const int t   = xcd * (NBLK / 8) + blockIdx.x / 8;
    float* __restrict__ sum_same = sum_same8 + (size_t)xcd * N;
    float* __restrict__ sum_all  = sum_all8  + (size_t)xcd * N;

    // ---- decode upper-triangular block index: t -> (bi, bj), bi<=bj ----
    int bj = (int)((sqrtf(8.f * (float)t + 1.f) - 1.f) * 0.5f);
    while ((bj + 1) * (bj + 2) / 2 <= t) ++bj;
    while (bj * (bj + 1) / 2 > t) --bj;
    const int bi    = t - bj * (bj + 1) / 2;
    const bool diag = (bi == bj);
    const int i0 = bi * TILE;
    const int j0 = bj * TILE;

    const int tid  = threadIdx.x;
    const int w    = tid >> 6;
    const int lane = tid & 63;
    const int wm   = w >> 1;
    const int wn   = w & 1;
    const int cl   = lane & 15;
    const int g    = lane >> 4;

    f32x4 acc[4][4];
#pragma unroll
    for (int a = 0; a < 4; ++a)
#pragma unroll
        for (int b = 0; b < 4; ++b) acc[a][b] = (f32x4){0.f, 0.f, 0.f, 0.f};

    // staging: 512 16B-chunks per tile; chunk c -> row=c>>2, kc=c&3 (linear LDS)
    const int c0 = w * 64 + lane;
    const int r0 = c0 >> 2, kc0 = c0 & 3;
    const int c1 = 256 + c0;
    const int r1 = c1 >> 2, kc1 = c1 & 3;

    // every wave issues EXACTLY 4 global_load_lds per stage -> per-wave vmcnt
    // accounting is uniform and exact.
#define STAGE(buf, k0)                                                          \
    do {                                                                        \
        load_lds16(x16 + (size_t)(i0 + r0) * D + (k0) + kc0 * 8,                \
                   &As[buf][(size_t)(w * 64) * 8]);                             \
        load_lds16(x16 + (size_t)(j0 + r0) * D + (k0) + kc0 * 8,                \
                   &Bs[buf][(size_t)(w * 64) * 8]);                             \
        load_lds16(x16 + (size_t)(i0 + r1) * D + (k0) + kc1 * 8,                \
                   &As[buf][(size_t)(256 + w * 64) * 8]);                       \
        load_lds16(x16 + (size_t)(j0 + r1) * D + (k0) + kc1 * 8,                \
                   &Bs[buf][(size_t)(256 + w * 64) * 8]);                       \
    } while (0)

    STAGE(0, 0);           // prologue: stages 0 and 1 in flight (8 loads)
    STAGE(1, BK);

    const int colbase = j0 + wn * 64;
    float sqj_[4];
    int   yj_[4];

#pragma unroll
    for (int t8 = 0; t8 < 8; ++t8) {          // fully unrolled -> static %3
        const int cur = t8 % 3;
        if (t8 < 6) STAGE((t8 + 2) % 3, (t8 + 2) * BK);   // keep 2 stages ahead

        // wait for stage t8 only: 2 newer stages (8 loads) may stay in flight
        if (t8 < 6)       asm volatile("s_waitcnt vmcnt(8)" ::: "memory");
        else if (t8 == 6) asm volatile("s_waitcnt vmcnt(4)" ::: "memory");
        else              asm volatile("s_waitcnt vmcnt(0)" ::: "memory");
        __builtin_amdgcn_s_barrier();   // all waves' stage-t8 loads landed

        // last iter: issue epilogue operand loads; latency hides under MFMAs
        if (t8 == 7) {
#pragma unroll
            for (int nf = 0; nf < 4; ++nf) {
                const int c = colbase + nf * 16 + cl;
                sqj_[nf] = sq[c];
                yj_[nf]  = lbl[c];
            }
        }

        half8 af[4], bf[4];
#pragma unroll
        for (int mf = 0; mf < 4; ++mf)
            af[mf] = *(const half8*)&As[cur][(wm * 64 + mf * 16 + cl) * BK + g * 8];
#pragma unroll
        for (int nf = 0; nf < 4; ++nf)
            bf[nf] = *(const half8*)&Bs[cur][(wn * 64 + nf * 16 + cl) * BK + g * 8];

        __builtin_amdgcn_s_setprio(1);
#pragma unroll
        for (int mf = 0; mf < 4; ++mf)
#pragma unroll
            for (int nf = 0; nf < 4; ++nf)
                acc[mf][nf] = __builtin_amdgcn_mfma_f32_16x16x32_f16(
                    af[mf], bf[nf], acc[mf][nf], 0, 0, 0);
        __builtin_amdgcn_s_setprio(0);

        // all waves consumed buf[cur] -> next iter's stage may overwrite it
        __builtin_amdgcn_s_barrier();
    }
#undef STAGE

    // ---- epilogue (r7/r10-verified) ----
    // C layout (m89): col = lane&15 (j-local), row = (lane>>4)*4 + reg (i-local)
    const int rowbase = i0 + wm * 64;

    float cs_all[4], cs_same[4];      // col sums (over i) -> rows of panel bj
#pragma unroll
    for (int nf = 0; nf < 4; ++nf) { cs_all[nf] = 0.f; cs_same[nf] = 0.f; }

    // two batches of 8 rows each (mf in {2b, 2b+1}) to limit register peak
#pragma unroll
    for (int b = 0; b < 2; ++b) {
        float rs_all[8], rs_same[8];
#pragma unroll
        for (int e = 0; e < 8; ++e) { rs_all[e] = 0.f; rs_same[e] = 0.f; }

#pragma unroll
        for (int mh = 0; mh < 2; ++mh) {
            const int mf = 2 * b + mh;
#pragma unroll
            for (int r = 0; r < 4; ++r) {
                const int row   = rowbase + mf * 16 + g * 4 + r;
                const float sqi = sq[row];
                const int   yi  = lbl[row];
#pragma unroll
                for (int nf = 0; nf < 4; ++nf) {
                    float d2   = sqi + sqj_[nf] - 2.f * acc[mf][nf][r];
                    float dist = __builtin_amdgcn_sqrtf(fmaxf(d2, EPS_F));
                    if (diag) {
                        const int col = colbase + nf * 16 + cl;
                        if (row == col) dist = 1e-5f;   // exact diagonal sqrt(EPS)
                    }
                    const float dm = (yi == yj_[nf]) ? dist : 0.f;
                    cs_all[nf] += dist;
                    cs_same[nf] += dm;
                    rs_all[mh * 4 + r] += dist;
                    rs_same[mh * 4 + r] += dm;
                }
            }
        }

        // row direction (off-diag only): value-split 8 values over 16 lanes,
        // closing mask-1 stage completes the 16-lane sum; even-cl lanes own
        // entry e = cl>>1.
        if (!diag) {
#define RSTEP(h, mask, bit)                                                     \
            {                                                                   \
                const bool hi = (cl >> (bit)) & 1;                              \
                _Pragma("unroll")                                               \
                for (int j = 0; j < (h); ++j) {                                 \
                    float sa_ = hi ? rs_all[j] : rs_all[j + (h)];               \
                    float ka_ = hi ? rs_all[j + (h)] : rs_all[j];               \
                    rs_all[j] = ka_ + __shfl_xor(sa_, (mask));                  \
                    float ss_ = hi ? rs_same[j] : rs_same[j + (h)];             \
                    float ks_ = hi ? rs_same[j + (h)] : rs_same[j];             \
                    rs_same[j] = ks_ + __shfl_xor(ss_, (mask));                 \
                }                                                               \
            }
            RSTEP(4, 8, 3)
            RSTEP(2, 4, 2)
            RSTEP(1, 2, 1)
#undef RSTEP
            rs_all[0]  += __shfl_xor(rs_all[0], 1);   // closing stage (mask 1)
            rs_same[0] += __shfl_xor(rs_same[0], 1);

            const int e    = cl >> 1;
            const int rrow = rowbase + (2 * b + (e >> 2)) * 16 + g * 4 + (e & 3);
            if (!(cl & 1)) {
                atomicAdd(&sum_all[rrow],  rs_all[0]);
                atomicAdd(&sum_same[rrow], rs_same[0]);
            }
        }
    }

    // ---- col direction: value-split reduce 4 values over 4 g-lanes
    {
        const bool hi1 = (g >> 1) & 1;
#pragma unroll
        for (int j = 0; j < 2; ++j) {
            float sa_ = hi1 ? cs_all[j] : cs_all[j + 2];
            float ka_ = hi1 ? cs_all[j + 2] : cs_all[j];
            cs_all[j] = ka_ + __shfl_xor(sa_, 32);
            float ss_ = hi1 ? cs_same[j] : cs_same[j + 2];
            float ks_ = hi1 ? cs_same[j + 2] : cs_same[j];
            cs_same[j] = ks_ + __shfl_xor(ss_, 32);
        }
        const bool hi0 = g & 1;
        {
            float sa_ = hi0 ? cs_all[0] : cs_all[1];
            float ka_ = hi0 ? cs_all[1] : cs_all[0];
            cs_all[0] = ka_ + __shfl_xor(sa_, 16);
            float ss_ = hi0 ? cs_same[0] : cs_same[1];
            float ks_ = hi0 ? cs_same[1] : cs_same[0];
            cs_same[0] = ks_ + __shfl_xor(ss_, 16);
        }
        const int ccol = colbase + g * 16 + cl;
        atomicAdd(&sum_all[ccol],  cs_all[0]);
        atomicAdd(&sum_same[ccol], cs_same[0]);
    }
}

// ---------------------------------------------------------------------------
// Finalize: 32 blocks x 256 thr, one row per thread. Sums the 8 per-XCD
// partials; histogram from the 16 precomputed slices.
// ---------------------------------------------------------------------------
__global__ void finalize_kernel(const float* __restrict__ sum_same8,
                                const float* __restrict__ sum_all8,
                                const int* __restrict__ lbl,
                                const int* __restrict__ hist16,
                                float* __restrict__ out) {
    __shared__ int lh[64];
    __shared__ float wsums[4];
    const int tid = threadIdx.x;
    if (tid < 64) {
        int h = 0;
#pragma unroll
        for (int b = 0; b < 16; ++b) h += hist16[b * 64 + tid];
        lh[tid] = h;
    }
    __syncthreads();

    const int row = blockIdx.x * 256 + tid;
    float ss = 0.f, sa = 0.f;
#pragma unroll
    for (int x = 0; x < 8; ++x) {
        ss += sum_same8[(size_t)x * N + row];
        sa += sum_all8[(size_t)x * N + row];
    }

    const float cnt = (float)lh[lbl[row]];
    const float ap  = ss / cnt;
    const float an  = (sa - ss) / ((float)N - cnt);
    float local = fmaxf(ap - an + MARGIN, 0.f);

#pragma unroll
    for (int off = 32; off > 0; off >>= 1) local += __shfl_down(local, off);
    const int lane = tid & 63, wave = tid >> 6;
    if (lane == 0) wsums[wave] = local;
    __syncthreads();
    if (tid == 0)
        atomicAdd(out, (wsums[0] + wsums[1] + wsums[2] + wsums[3]) / (float)N);
}

// ---------------------------------------------------------------------------
extern "C" void kernel_launch(void* const* d_in, const int* in_sizes, int n_in,
                              void* d_out, int out_size, void* d_ws, size_t ws_size,
                              hipStream_t stream) {
    const float* xs     = (const float*)d_in[0];
    const int*   ys_raw = (const int*)d_in[1];

    float* ws        = (float*)d_ws;
    float* sum_same8 = ws;                         // [8][N]
    float* sum_all8  = ws + 8 * N;                 // [8][N]
    float* sqv       = ws + 16 * N;                // [N]
    int*   lbl       = (int*)(ws + 17 * N);        // [N]
    int*   hist16    = (int*)(ws + 18 * N);        // [16*64]
    _Float16* x16    = (_Float16*)(ws + 18 * N + 1024);  // [N*D] fp16 (4 MB)

    prep_kernel<<<N / 16, 256, 0, stream>>>(xs, ys_raw, x16, sqv, lbl, hist16,
                                            sum_same8, (float*)d_out);

    pair_kernel<<<NBLK, 256, 0, stream>>>(x16, lbl, sqv, sum_same8, sum_all8);

    finalize_kernel<<<32, 256, 0, stream>>>(sum_same8, sum_all8, lbl, hist16,
                                            (float*)d_out);
}

// Round 16
// 49.789 us; speedup vs baseline: 1.7073x; 1.0256x over previous
//
#include <hip/hip_runtime.h>
#include <math.h>

#define N 8192
#define D 256
#define BK 32
#define TILE 128
#define NB (N / TILE)              // 64 panels
#define NBLK (NB * (NB + 1) / 2)   // 2080 upper-triangular blocks

typedef _Float16 half8 __attribute__((ext_vector_type(8)));
typedef float f32x4 __attribute__((ext_vector_type(4)));

constexpr float MARGIN = 0.5f;
constexpr float EPS_F  = 1e-10f;

// ---------------------------------------------------------------------------
// async global->LDS, 16B per lane. LDS dest = wave-uniform base + lane*16.
// ---------------------------------------------------------------------------
__device__ inline void load_lds16(const void* g, void* l) {
    __builtin_amdgcn_global_load_lds(
        (const __attribute__((address_space(1))) void*)g,
        (__attribute__((address_space(3))) void*)l, 16, 0, 0);
}

// ---------------------------------------------------------------------------
// Fused prologue (one dispatch, 512 blocks x 256 thr):
//   all blocks  : fp32 -> fp16 row-major convert + exact fp32 row sq-norms
//   blocks 0-15 : label detect/normalize + per-block 64-bin histogram slice
//   blocks 16-47: zero the 8 per-XCD partial sum arrays (16N floats)
//   block 48    : zero out[0]
// ---------------------------------------------------------------------------
__global__ void prep_kernel(const float* __restrict__ xs,
                            const int* __restrict__ ys_raw,
                            _Float16* __restrict__ x16, float* __restrict__ sq,
                            int* __restrict__ lbl, int* __restrict__ hist16,
                            float* __restrict__ sums, float* __restrict__ out) {
    const int tid = threadIdx.x;
    const int rb  = blockIdx.x;

    // ---- convert + sq (every block handles a 16-row tile) ----
    {
        const int r   = tid >> 4;
        const int c16 = tid & 15;
        const int row = rb * 16 + r;

        const float4* src = (const float4*)xs + (size_t)row * (D / 4) + c16 * 4;
        const float4 v0 = src[0], v1 = src[1], v2 = src[2], v3 = src[3];

        half8 h0 = { (_Float16)v0.x, (_Float16)v0.y, (_Float16)v0.z, (_Float16)v0.w,
                     (_Float16)v1.x, (_Float16)v1.y, (_Float16)v1.z, (_Float16)v1.w };
        half8 h1 = { (_Float16)v2.x, (_Float16)v2.y, (_Float16)v2.z, (_Float16)v2.w,
                     (_Float16)v3.x, (_Float16)v3.y, (_Float16)v3.z, (_Float16)v3.w };

        _Float16* dst = x16 + (size_t)row * D + c16 * 16;
        *(half8*)dst       = h0;
        *(half8*)(dst + 8) = h1;

        float s = v0.x*v0.x + v0.y*v0.y + v0.z*v0.z + v0.w*v0.w
                + v1.x*v1.x + v1.y*v1.y + v1.z*v1.z + v1.w*v1.w
                + v2.x*v2.x + v2.y*v2.y + v2.z*v2.z + v2.w*v2.w
                + v3.x*v3.x + v3.y*v3.y + v3.z*v3.z + v3.w*v3.w;
#pragma unroll
        for (int off = 1; off < 16; off <<= 1) s += __shfl_xor(s, off);
        if (c16 == 0) sq[row] = s;
    }

    // ---- labels + histogram slice (blocks 0-15, 512 labels each) ----
    if (rb < 16) {
        __shared__ int bad_s;
        __shared__ int lh[64];
        const int base = rb * 512;
        if (tid == 0) bad_s = 0;
        if (tid < 64) lh[tid] = 0;
        __syncthreads();
        int bad = 0;
        for (int i = tid; i < 512; i += 256) bad |= (ys_raw[2 * (base + i) + 1] != 0);
        if (bad) atomicOr(&bad_s, 1);
        __syncthreads();
        const bool is64 = (bad_s == 0);
        for (int i = tid; i < 512; i += 256) {
            const int v = is64 ? ys_raw[2 * (base + i)] : ys_raw[base + i];
            lbl[base + i] = v;
            atomicAdd(&lh[v & 63], 1);
        }
        __syncthreads();
        if (tid < 64) hist16[rb * 64 + tid] = lh[tid];   // exclusive slice
    }

    // ---- zero per-XCD partials (blocks 16-47: 32 blocks x 4096 floats = 16N) ----
    if (rb >= 16 && rb < 48) {
        const int base = (rb - 16) * 4096;
#pragma unroll
        for (int k = 0; k < 16; ++k) sums[base + k * 256 + tid] = 0.f;
    }
    if (rb == 48 && tid == 0) out[0] = 0.f;
}

// ---------------------------------------------------------------------------
// Symmetric MFMA pair kernel (r15 base), SINGLE-barrier 3-buffer ring:
// per k-iter: vmcnt(4) -> barrier -> STAGE(t+2) -> ds_read -> MFMA.
// Safety: stage of tile t+2 writes buf (t+2)%3 == (t-1)%3, whose readers all
// completed before barrier(t) (ds_read is lgkmcnt-gated before MFMA issue,
// which precedes each wave's barrier). Steady vmcnt(4) is per-wave exact
// (outstanding = tiles {t, t+1} = 8 at the wait -> drains tile t).
// 128x128 tile, 4 waves (2x2 of 64x64), setprio on MFMA, per-XCD atomics.
// ---------------------------------------------------------------------------
__global__ __launch_bounds__(256, 3) void pair_kernel(
    const _Float16* __restrict__ x16, const int* __restrict__ lbl,
    const float* __restrict__ sq,
    float* __restrict__ sum_same8, float* __restrict__ sum_all8) {

    __shared__ _Float16 As[3][TILE * BK];   // 24 KB
    __shared__ _Float16 Bs[3][TILE * BK];   // 24 KB

    // ---- XCD-bijective swizzle (2080 % 8 == 0 -> exact chunking) ----
    const int xcd = blockIdx.x & 7;         // == XCD under round-robin dispatch
    const int t   = xcd * (NBLK / 8) + blockIdx.x / 8;
    float* __restrict__ sum_same = sum_same8 + (size_t)xcd * N;
    float* __restrict__ sum_all  = sum_all8  + (size_t)xcd * N;

    // ---- decode upper-triangular block index: t -> (bi, bj), bi<=bj ----
    int bj = (int)((sqrtf(8.f * (float)t + 1.f) - 1.f) * 0.5f);
    while ((bj + 1) * (bj + 2) / 2 <= t) ++bj;
    while (bj * (bj + 1) / 2 > t) --bj;
    const int bi    = t - bj * (bj + 1) / 2;
    const bool diag = (bi == bj);
    const int i0 = bi * TILE;
    const int j0 = bj * TILE;

    const int tid  = threadIdx.x;
    const int w    = tid >> 6;
    const int lane = tid & 63;
    const int wm   = w >> 1;
    const int wn   = w & 1;
    const int cl   = lane & 15;
    const int g    = lane >> 4;

    f32x4 acc[4][4];
#pragma unroll
    for (int a = 0; a < 4; ++a)
#pragma unroll
        for (int b = 0; b < 4; ++b) acc[a][b] = (f32x4){0.f, 0.f, 0.f, 0.f};

    // staging: 512 16B-chunks per tile; chunk c -> row=c>>2, kc=c&3 (linear LDS)
    const int c0 = w * 64 + lane;
    const int r0 = c0 >> 2, kc0 = c0 & 3;
    const int c1 = 256 + c0;
    const int r1 = c1 >> 2, kc1 = c1 & 3;

    // every wave issues EXACTLY 4 global_load_lds per stage -> per-wave vmcnt
    // accounting is uniform and exact.
#define STAGE(buf, k0)                                                          \
    do {                                                                        \
        load_lds16(x16 + (size_t)(i0 + r0) * D + (k0) + kc0 * 8,                \
                   &As[buf][(size_t)(w * 64) * 8]);                             \
        load_lds16(x16 + (size_t)(j0 + r0) * D + (k0) + kc0 * 8,                \
                   &Bs[buf][(size_t)(w * 64) * 8]);                             \
        load_lds16(x16 + (size_t)(i0 + r1) * D + (k0) + kc1 * 8,                \
                   &As[buf][(size_t)(256 + w * 64) * 8]);                       \
        load_lds16(x16 + (size_t)(j0 + r1) * D + (k0) + kc1 * 8,                \
                   &Bs[buf][(size_t)(256 + w * 64) * 8]);                       \
    } while (0)

    STAGE(0, 0);           // prologue: stages 0 and 1 in flight (8 loads)
    STAGE(1, BK);

    const int colbase = j0 + wn * 64;
    float sqj_[4];
    int   yj_[4];

#pragma unroll
    for (int t8 = 0; t8 < 8; ++t8) {          // fully unrolled -> static %3
        const int cur = t8 % 3;

        // wait for tile t8 only: tile t8+1 (4 loads) stays in flight
        if (t8 < 7) asm volatile("s_waitcnt vmcnt(4)" ::: "memory");
        else        asm volatile("s_waitcnt vmcnt(0)" ::: "memory");
        __builtin_amdgcn_s_barrier();   // all waves' tile-t8 loads landed AND
                                        // all waves done reading buf (t8-1)%3

        // stage tile t8+2 into buf (t8+2)%3 == (t8-1)%3 — safe after barrier
        if (t8 < 6) STAGE((t8 + 2) % 3, (t8 + 2) * BK);

        // last iter: issue epilogue operand loads; latency hides under MFMAs
        if (t8 == 7) {
#pragma unroll
            for (int nf = 0; nf < 4; ++nf) {
                const int c = colbase + nf * 16 + cl;
                sqj_[nf] = sq[c];
                yj_[nf]  = lbl[c];
            }
        }

        half8 af[4], bf[4];
#pragma unroll
        for (int mf = 0; mf < 4; ++mf)
            af[mf] = *(const half8*)&As[cur][(wm * 64 + mf * 16 + cl) * BK + g * 8];
#pragma unroll
        for (int nf = 0; nf < 4; ++nf)
            bf[nf] = *(const half8*)&Bs[cur][(wn * 64 + nf * 16 + cl) * BK + g * 8];

        __builtin_amdgcn_s_setprio(1);
#pragma unroll
        for (int mf = 0; mf < 4; ++mf)
#pragma unroll
            for (int nf = 0; nf < 4; ++nf)
                acc[mf][nf] = __builtin_amdgcn_mfma_f32_16x16x32_f16(
                    af[mf], bf[nf], acc[mf][nf], 0, 0, 0);
        __builtin_amdgcn_s_setprio(0);
        // no trailing barrier: next iter's leading barrier provides the
        // consume-done guarantee for the ring buffer.
    }
#undef STAGE

    // ---- epilogue (r7/r10-verified) ----
    // C layout (m89): col = lane&15 (j-local), row = (lane>>4)*4 + reg (i-local)
    const int rowbase = i0 + wm * 64;

    float cs_all[4], cs_same[4];      // col sums (over i) -> rows of panel bj
#pragma unroll
    for (int nf = 0; nf < 4; ++nf) { cs_all[nf] = 0.f; cs_same[nf] = 0.f; }

    // two batches of 8 rows each (mf in {2b, 2b+1}) to limit register peak
#pragma unroll
    for (int b = 0; b < 2; ++b) {
        float rs_all[8], rs_same[8];
#pragma unroll
        for (int e = 0; e < 8; ++e) { rs_all[e] = 0.f; rs_same[e] = 0.f; }

#pragma unroll
        for (int mh = 0; mh < 2; ++mh) {
            const int mf = 2 * b + mh;
#pragma unroll
            for (int r = 0; r < 4; ++r) {
                const int row   = rowbase + mf * 16 + g * 4 + r;
                const float sqi = sq[row];
                const int   yi  = lbl[row];
#pragma unroll
                for (int nf = 0; nf < 4; ++nf) {
                    float d2   = sqi + sqj_[nf] - 2.f * acc[mf][nf][r];
                    float dist = __builtin_amdgcn_sqrtf(fmaxf(d2, EPS_F));
                    if (diag) {
                        const int col = colbase + nf * 16 + cl;
                        if (row == col) dist = 1e-5f;   // exact diagonal sqrt(EPS)
                    }
                    const float dm = (yi == yj_[nf]) ? dist : 0.f;
                    cs_all[nf] += dist;
                    cs_same[nf] += dm;
                    rs_all[mh * 4 + r] += dist;
                    rs_same[mh * 4 + r] += dm;
                }
            }
        }

        // row direction (off-diag only): value-split 8 values over 16 lanes,
        // closing mask-1 stage completes the 16-lane sum; even-cl lanes own
        // entry e = cl>>1.
        if (!diag) {
#define RSTEP(h, mask, bit)                                                     \
            {                                                                   \
                const bool hi = (cl >> (bit)) & 1;                              \
                _Pragma("unroll")                                               \
                for (int j = 0; j < (h); ++j) {                                 \
                    float sa_ = hi ? rs_all[j] : rs_all[j + (h)];               \
                    float ka_ = hi ? rs_all[j + (h)] : rs_all[j];               \
                    rs_all[j] = ka_ + __shfl_xor(sa_, (mask));                  \
                    float ss_ = hi ? rs_same[j] : rs_same[j + (h)];             \
                    float ks_ = hi ? rs_same[j + (h)] : rs_same[j];             \
                    rs_same[j] = ks_ + __shfl_xor(ss_, (mask));                 \
                }                                                               \
            }
            RSTEP(4, 8, 3)
            RSTEP(2, 4, 2)
            RSTEP(1, 2, 1)
#undef RSTEP
            rs_all[0]  += __shfl_xor(rs_all[0], 1);   // closing stage (mask 1)
            rs_same[0] += __shfl_xor(rs_same[0], 1);

            const int e    = cl >> 1;
            const int rrow = rowbase + (2 * b + (e >> 2)) * 16 + g * 4 + (e & 3);
            if (!(cl & 1)) {
                atomicAdd(&sum_all[rrow],  rs_all[0]);
                atomicAdd(&sum_same[rrow], rs_same[0]);
            }
        }
    }

    // ---- col direction: value-split reduce 4 values over 4 g-lanes
    {
        const bool hi1 = (g >> 1) & 1;
#pragma unroll
        for (int j = 0; j < 2; ++j) {
            float sa_ = hi1 ? cs_all[j] : cs_all[j + 2];
            float ka_ = hi1 ? cs_all[j + 2] : cs_all[j];
            cs_all[j] = ka_ + __shfl_xor(sa_, 32);
            float ss_ = hi1 ? cs_same[j] : cs_same[j + 2];
            float ks_ = hi1 ? cs_same[j + 2] : cs_same[j];
            cs_same[j] = ks_ + __shfl_xor(ss_, 32);
        }
        const bool hi0 = g & 1;
        {
            float sa_ = hi0 ? cs_all[0] : cs_all[1];
            float ka_ = hi0 ? cs_all[1] : cs_all[0];
            cs_all[0] = ka_ + __shfl_xor(sa_, 16);
            float ss_ = hi0 ? cs_same[0] : cs_same[1];
            float ks_ = hi0 ? cs_same[1] : cs_same[0];
            cs_same[0] = ks_ + __shfl_xor(ss_, 16);
        }
        const int ccol = colbase + g * 16 + cl;
        atomicAdd(&sum_all[ccol],  cs_all[0]);
        atomicAdd(&sum_same[ccol], cs_same[0]);
    }
}

// ---------------------------------------------------------------------------
// Finalize: 32 blocks x 256 thr, one row per thread. Sums the 8 per-XCD
// partials; histogram from the 16 precomputed slices.
// ---------------------------------------------------------------------------
__global__ void finalize_kernel(const float* __restrict__ sum_same8,
                                const float* __restrict__ sum_all8,
                                const int* __restrict__ lbl,
                                const int* __restrict__ hist16,
                                float* __restrict__ out) {
    __shared__ int lh[64];
    __shared__ float wsums[4];
    const int tid = threadIdx.x;
    if (tid < 64) {
        int h = 0;
#pragma unroll
        for (int b = 0; b < 16; ++b) h += hist16[b * 64 + tid];
        lh[tid] = h;
    }
    __syncthreads();

    const int row = blockIdx.x * 256 + tid;
    float ss = 0.f, sa = 0.f;
#pragma unroll
    for (int x = 0; x < 8; ++x) {
        ss += sum_same8[(size_t)x * N + row];
        sa += sum_all8[(size_t)x * N + row];
    }

    const float cnt = (float)lh[lbl[row]];
    const float ap  = ss / cnt;
    const float an  = (sa - ss) / ((float)N - cnt);
    float local = fmaxf(ap - an + MARGIN, 0.f);

#pragma unroll
    for (int off = 32; off > 0; off >>= 1) local += __shfl_down(local, off);
    const int lane = tid & 63, wave = tid >> 6;
    if (lane == 0) wsums[wave] = local;
    __syncthreads();
    if (tid == 0)
        atomicAdd(out, (wsums[0] + wsums[1] + wsums[2] + wsums[3]) / (float)N);
}

// ---------------------------------------------------------------------------
extern "C" void kernel_launch(void* const* d_in, const int* in_sizes, int n_in,
                              void* d_out, int out_size, void* d_ws, size_t ws_size,
                              hipStream_t stream) {
    const float* xs     = (const float*)d_in[0];
    const int*   ys_raw = (const int*)d_in[1];

    float* ws        = (float*)d_ws;
    float* sum_same8 = ws;                         // [8][N]
    float* sum_all8  = ws + 8 * N;                 // [8][N]
    float* sqv       = ws + 16 * N;                // [N]
    int*   lbl       = (int*)(ws + 17 * N);        // [N]
    int*   hist16    = (int*)(ws + 18 * N);        // [16*64]
    _Float16* x16    = (_Float16*)(ws + 18 * N + 1024);  // [N*D] fp16 (4 MB)

    prep_kernel<<<N / 16, 256, 0, stream>>>(xs, ys_raw, x16, sqv, lbl, hist16,
                                            sum_same8, (float*)d_out);

    pair_kernel<<<NBLK, 256, 0, stream>>>(x16, lbl, sqv, sum_same8, sum_all8);

    finalize_kernel<<<32, 256, 0, stream>>>(sum_same8, sum_all8, lbl, hist16,
                                            (float*)d_out);
}